// Round 2
// baseline (99.068 us; speedup 1.0000x reference)
//
#include <hip/hip_runtime.h>

// Problem constants (KANLayer): B=1024, I=128, O=128, H=5
#define Bsz 1024
#define Isz 128
#define Osz 128
#define Hsz 5
#define Esz (Osz * Isz)   // 16384 edges
#define REC 48            // padded param record (floats): 192 B, 64B-aligned stride
                          // [0:5) W1 | [5:10) B1 | [10:35) W2 | [35:40) B2 | [40:45) W3 | [45] B3

// ---------------------------------------------------------------------------
// Param relayout: pt2[e][j] = j-th param of edge e, contiguous 48-float
// records so the main kernel can pull a whole edge with 3 s_load_dwordx16.
// Writes fully coalesced; reads mildly strided (L2-absorbed, one-time, 3 MB).
// ---------------------------------------------------------------------------
__global__ __launch_bounds__(256)
void relayout_params(const float* __restrict__ W1, const float* __restrict__ B1,
                     const float* __restrict__ W2, const float* __restrict__ B2,
                     const float* __restrict__ W3, const float* __restrict__ B3,
                     float* __restrict__ pt2) {
    const int idx = blockIdx.x * 256 + threadIdx.x;   // < Esz * REC
    const unsigned e = (unsigned)idx / REC;           // magic-mul div
    const int j = idx - (int)e * REC;
    float v = 0.0f;
    if (j < 5)        v = W1[e * 5 + j];
    else if (j < 10)  v = B1[e * 5 + (j - 5)];
    else if (j < 35)  v = W2[e * 25 + (j - 10)];
    else if (j < 40)  v = B2[e * 5 + (j - 35)];
    else if (j < 45)  v = W3[e * 5 + (j - 40)];
    else if (j == 45) v = B3[e];
    pt2[idx] = v;
}

// ---------------------------------------------------------------------------
// Batch-lane kernel (R10 restructure).
//   lane  <-> batch  (64 batches per wave, b = b0 + lane)
//   wave  <-> i-quarter (32 i's), params wave-uniform -> SGPRs via s_load
//   block <-> (o, batch-group of 64): 256 threads = 4 waves, grid 128x16=2048
// Per lane: 32 x-values held in VGPRs (full unroll -> static indices), the
// i-sum is a plain serial accumulator. No per-batch cross-lane reduction,
// no LDS in the hot loop, no 46-VGPR param set. One 1 KB LDS combine at end.
// Every out element written exactly once.
// ---------------------------------------------------------------------------
__global__ __launch_bounds__(256, 4)
void kan_kernel(const float* __restrict__ x,
                const float* __restrict__ pt2,
                float* __restrict__ out) {
    __shared__ float partial[4][64];   // 1 KB

    const int tid = threadIdx.x;
    const int o   = blockIdx.x & (Osz - 1);   // o fastest: neighbor blocks share x tile
    const int bg  = blockIdx.x >> 7;          // 16 batch groups
    const int b0  = bg * 64;
    const int l   = tid & 63;
    // wave id as a provably wave-uniform (SGPR) value -> param addrs uniform
    const int wu  = __builtin_amdgcn_readfirstlane(tid >> 6);

    // --- my batch row's i-quarter -> 32 VGPRs (8x float4; 16B aligned) ---
    float xr[32];
    {
        const float4* xrow = (const float4*)(x + (size_t)(b0 + l) * Isz + 32 * wu);
        #pragma unroll
        for (int c = 0; c < 8; ++c) {
            const float4 v = xrow[c];
            xr[4 * c + 0] = v.x; xr[4 * c + 1] = v.y;
            xr[4 * c + 2] = v.z; xr[4 * c + 3] = v.w;
        }
    }

    // wave-uniform param base for this wave's 32 edges
    const float* __restrict__ pbase = pt2 + (size_t)(o * Isz + 32 * wu) * REC;

    float acc = 0.0f;   // sum over this wave's i-quarter for batch b0+l

    #pragma unroll
    for (int ii = 0; ii < 32; ++ii) {
        const float* __restrict__ p = pbase + ii * REC;   // uniform + imm offsets
        const float a = xr[ii];

        // layer 1: scalar -> H, leaky_relu(0.01); p[h]/p[5+h] are SGPRs
        float h1[Hsz];
        #pragma unroll
        for (int h = 0; h < Hsz; ++h) {
            const float v = fmaf(a, p[h], p[5 + h]);
            h1[h] = fmaxf(v, 0.01f * v);
        }
        // layer 2 (H->H, lrelu) + layer 3 (H->1) + b3, all SGPR weights
        float yy = p[45];
        #pragma unroll
        for (int k = 0; k < Hsz; ++k) {
            float s = p[35 + k];
            #pragma unroll
            for (int h = 0; h < Hsz; ++h)
                s = fmaf(h1[h], p[10 + k * Hsz + h], s);
            s = fmaxf(s, 0.01f * s);
            yy = fmaf(s, p[40 + k], yy);
        }
        acc += yy;
    }

    partial[wu][l] = acc;
    __syncthreads();

    // combine the 4 i-quarters; 64 outputs per block, each written once
    if (tid < 64) {
        const float v = partial[0][tid] + partial[1][tid]
                      + partial[2][tid] + partial[3][tid];
        out[(size_t)(b0 + tid) * Osz + o] = v;
    }
}

extern "C" void kernel_launch(void* const* d_in, const int* in_sizes, int n_in,
                              void* d_out, int out_size, void* d_ws, size_t ws_size,
                              hipStream_t stream) {
    const float* x  = (const float*)d_in[0];
    const float* W1 = (const float*)d_in[1];
    const float* B1 = (const float*)d_in[2];
    const float* W2 = (const float*)d_in[3];
    const float* B2 = (const float*)d_in[4];
    const float* W3 = (const float*)d_in[5];
    const float* B3 = (const float*)d_in[6];
    float* out = (float*)d_out;
    float* pt2 = (float*)d_ws;   // 16384 * 48 * 4 B = 3.0 MB << ws_size

    // 1) one-time aligned param-record relayout into workspace
    relayout_params<<<dim3(Esz * REC / 256), dim3(256), 0, stream>>>(
        W1, B1, W2, B2, W3, B3, pt2);

    // 2) batch-lane main kernel
    kan_kernel<<<dim3(Osz * (Bsz / 64)), dim3(256), 0, stream>>>(x, pt2, out);
}